// Round 1
// 240.975 us; speedup vs baseline: 1.0479x; 1.0479x over previous
//
#include <hip/hip_runtime.h>
#include <stdint.h>

// B=4, n=8192, d=512.  Algebraic form:
//   G_b = X_b^T X_b                       [512,512] sym, K=8192
//   kvt_b = Wv * (G_b*scale) * Wth^T      [e][d], scale = 1/(n*sqrt(d))
//   meanV_b[e] = colmean(X_b) . Wv[e][:]
//   out = X_b @ kvt_b(B-layout) + meanV
// Layouts (all K-inner for global_load_lds staging):
//   Xb  [32768][512] bf16        A for final GEMM
//   Xt  [4][512][8192] bf16      A=B for G GEMM (n-inner)
//   Gb  [4][512][512] bf16       scaled, full (mirrored from upper tiles)

typedef __bf16 bf16x8 __attribute__((ext_vector_type(8)));
typedef float f32x4 __attribute__((ext_vector_type(4)));
typedef unsigned short u16x4 __attribute__((ext_vector_type(4)));
typedef unsigned short u16x8 __attribute__((ext_vector_type(8)));

#define BM 128
#define BN 128
#define BK 32

#define VM4 asm volatile("s_waitcnt vmcnt(4)" ::: "memory")
#define VM2 asm volatile("s_waitcnt vmcnt(2)" ::: "memory")
#define VM0 asm volatile("s_waitcnt vmcnt(0)" ::: "memory")
#define BAR asm volatile("s_barrier" ::: "memory")

__device__ __forceinline__ unsigned short f2bf(float f) {
  union { float f; unsigned int u; } c; c.f = f;
  unsigned int u = c.u;
  return (unsigned short)((u + 0x7FFFu + ((u >> 16) & 1u)) >> 16);  // RNE
}
__device__ __forceinline__ float bf2f(unsigned short h) {
  union { unsigned int u; float f; } c; c.u = ((unsigned int)h) << 16;
  return c.f;
}

__device__ __forceinline__ void gld16(const void* g, void* l) {
  using gptr_t = const __attribute__((address_space(1))) void*;
  using lptr_t = __attribute__((address_space(3))) void*;
  __builtin_amdgcn_global_load_lds((gptr_t)(uintptr_t)g,
                                   (lptr_t)(uint32_t)(uintptr_t)l, 16, 0, 0);
}

// 128x128 tile GEMM core: C[m][n] = sum_k A[m0+m][k] * B[n0+n][k]
// T3-min/T4 pipeline: stage tile t+1 before computing tile t, counted vmcnt
// (never 0 in-loop) so next-tile loads stay in flight across the barrier.
// K must be a multiple of 64. If sameAB, B staging is skipped (B==A tile).
__device__ __forceinline__ void gemm_tile(const unsigned short* __restrict__ A, int lda,
                                          const unsigned short* __restrict__ B, int ldb,
                                          int K, int m0, int n0, f32x4 (&acc)[4][4],
                                          bool sameAB) {
  __shared__ unsigned short sA[2][BM * BK];
  __shared__ unsigned short sB[2][BN * BK];
  const int tid = threadIdx.x;
  const int lane = tid & 63;
  const int w = tid >> 6;
  const int wm = w >> 1, wn = w & 1;
  const int quad = lane >> 4, l16 = lane & 15;

#pragma unroll
  for (int mi = 0; mi < 4; mi++)
#pragma unroll
    for (int ni = 0; ni < 4; ni++) acc[mi][ni] = f32x4{0.f, 0.f, 0.f, 0.f};

  auto stage = [&](int bb, int kk) {
#pragma unroll
    for (int j = 0; j < 2; j++) {
      const int slot = w * 128 + j * 64 + lane;
      const int row = slot >> 2;
      const int col = (slot & 3) * 8;
      gld16(A + (size_t)(m0 + row) * lda + kk + col,
            (char*)sA[bb] + (size_t)(w * 128 + j * 64) * 16);
      if (!sameAB)
        gld16(B + (size_t)(n0 + row) * ldb + kk + col,
              (char*)sB[bb] + (size_t)(w * 128 + j * 64) * 16);
    }
  };

  auto compute = [&](int bb) {
    const unsigned short* as = sA[bb];
    const unsigned short* bs = sameAB ? sA[bb] : sB[bb];
    bf16x8 af[4], bfr[4];
#pragma unroll
    for (int mi = 0; mi < 4; mi++)
      af[mi] = *(const bf16x8*)&as[(wm * 64 + mi * 16 + l16) * BK + quad * 8];
#pragma unroll
    for (int ni = 0; ni < 4; ni++)
      bfr[ni] = *(const bf16x8*)&bs[(wn * 64 + ni * 16 + l16) * BK + quad * 8];
#pragma unroll
    for (int mi = 0; mi < 4; mi++)
#pragma unroll
      for (int ni = 0; ni < 4; ni++)
        acc[mi][ni] = __builtin_amdgcn_mfma_f32_16x16x32_bf16(af[mi], bfr[ni],
                                                              acc[mi][ni], 0, 0, 0);
  };

  stage(0, 0);
  for (int kt = 0; kt < K; kt += 2 * BK) {
    stage(1, kt + BK);
    if (sameAB) { VM2; } else { VM4; }
    BAR;
    compute(0);
    BAR;
    if (kt + 2 * BK < K) {
      stage(0, kt + 2 * BK);
      if (sameAB) { VM2; } else { VM4; }
    } else {
      VM0;
    }
    BAR;
    compute(1);
    BAR;
  }
}

// ---- prep: X fp32 -> Xb bf16 + Xt bf16 (per-batch transpose), fused colsum ----
// 128n x 64d tile per block (2x per-thread MLP vs 64x64), column-sum of the
// bf16 values folded into the Xt store phase (shfl-reduce + 64 atomics/block).
__global__ __launch_bounds__(256) void prep_kernel(const float* __restrict__ X,
                                                   unsigned short* __restrict__ Xb,
                                                   unsigned short* __restrict__ Xt,
                                                   float* __restrict__ mean_x) {
  __shared__ unsigned short sT[2][64 * 64];
  const int t = threadIdx.x;
  const int n0 = blockIdx.x * 128, d0 = blockIdx.y * 64;
  const int b = n0 >> 13, nb = n0 & 8191;
  const int r0 = (t >> 4) * 4, c0 = (t & 15) * 4;
  f32x4 v[2][4];
#pragma unroll
  for (int s = 0; s < 2; s++)
#pragma unroll
    for (int i = 0; i < 4; i++)
      v[s][i] = *(const f32x4*)(X + (size_t)(n0 + s * 64 + r0 + i) * 512 + d0 + c0);
  // Xb (row-major cast), coalesced 8B stores
#pragma unroll
  for (int s = 0; s < 2; s++)
#pragma unroll
    for (int i = 0; i < 4; i++) {
      u16x4 o;
#pragma unroll
      for (int j = 0; j < 4; j++) o[j] = f2bf(v[s][i][j]);
      *(u16x4*)(Xb + (size_t)(n0 + s * 64 + r0 + i) * 512 + d0 + c0) = o;
    }
  // transposed into LDS, XOR swizzle in 8-elem blocks (keeps u16x8 reads aligned)
#pragma unroll
  for (int s = 0; s < 2; s++)
#pragma unroll
    for (int j = 0; j < 4; j++) {
      u16x4 wv;
#pragma unroll
      for (int i = 0; i < 4; i++) wv[i] = f2bf(v[s][i][j]);
      const int c = c0 + j;
      const int rsw = r0 ^ (c & 0x38);
      *(u16x4*)&sT[s][c * 64 + rsw] = wv;
    }
  __syncthreads();
  // Xt stores: thread t -> cols c, c+32 (d-index), 8 n-elems each subtile, 16B stores
  const int cr = t >> 3, p = t & 7;
  float csum[2] = {0.f, 0.f};
#pragma unroll
  for (int s = 0; s < 2; s++)
#pragma unroll
    for (int h = 0; h < 2; h++) {
      const int c = cr + h * 32;
      const int phys = (p * 8) ^ (c & 0x38);
      u16x8 val = *(const u16x8*)&sT[s][c * 64 + phys];
      *(u16x8*)(Xt + (size_t)(b * 512 + d0 + c) * 8192 + nb + s * 64 + p * 8) = val;
      float ss = 0.f;
#pragma unroll
      for (int j = 0; j < 8; j++) ss += bf2f(val[j]);
      csum[h] += ss;
    }
  // reduce over the 8 p-threads of each (cr,h), one atomic per column
#pragma unroll
  for (int h = 0; h < 2; h++) {
    float sv = csum[h];
    sv += __shfl_xor(sv, 1);
    sv += __shfl_xor(sv, 2);
    sv += __shfl_xor(sv, 4);
    if (p == 0) atomicAdd(&mean_x[b * 512 + d0 + cr + h * 32], sv);
  }
}

// ---- W casts + zero-init of mean_x (runs before prep in-stream) ----
__global__ __launch_bounds__(256) void prep_w_kernel(const float* __restrict__ Wv,
                                                     const float* __restrict__ Wth,
                                                     unsigned short* __restrict__ Wvb,
                                                     unsigned short* __restrict__ Wtb,
                                                     float* __restrict__ mean_x) {
  const int blk = blockIdx.x;
  const int t = threadIdx.x;
  if (blk == 0) {
#pragma unroll
    for (int i = 0; i < 8; i++) mean_x[t + i * 256] = 0.f;
  }
  const float* src = (blk < 128) ? Wv : Wth;
  unsigned short* dst = (blk < 128) ? Wvb : Wtb;
  const int i = (blk & 127) * 256 + t;
  const f32x4* pp = (const f32x4*)(src + (size_t)i * 8);
  f32x4 v0 = pp[0], v1 = pp[1];
  u16x8 o;
  o[0] = f2bf(v0[0]); o[1] = f2bf(v0[1]); o[2] = f2bf(v0[2]); o[3] = f2bf(v0[3]);
  o[4] = f2bf(v1[0]); o[5] = f2bf(v1[1]); o[6] = f2bf(v1[2]); o[7] = f2bf(v1[3]);
  *(u16x8*)(dst + (size_t)i * 8) = o;
}

// ---- G = Xt Xt^T (per batch), split-K=16, upper tiles only ----
static __device__ const int TI[10] = {0, 0, 0, 0, 1, 1, 1, 2, 2, 3};
static __device__ const int TJ[10] = {0, 1, 2, 3, 1, 2, 3, 2, 3, 3};

__global__ __launch_bounds__(256) void g_gemm_kernel(const unsigned short* __restrict__ Xt,
                                                     float* __restrict__ G_part) {
  const int t = blockIdx.x;        // 0..9 upper tile
  const int z = blockIdx.y;        // b*16 + s
  const int b = z >> 4, s = z & 15;
  const int m0 = TI[t] * 128, n0 = TJ[t] * 128;
  const unsigned short* A = Xt + (size_t)b * 512 * 8192 + (size_t)s * 512;
  f32x4 acc[4][4];
  gemm_tile(A, 8192, A, 8192, 512, m0, n0, acc, m0 == n0);
  float* Cp = G_part + ((size_t)z * 10 + t) * 16384;  // tile stored [n_local][m_local]
  const int tid = threadIdx.x, lane = tid & 63, w = tid >> 6;
  const int wm = w >> 1, wn = w & 1, quad = lane >> 4, l16 = lane & 15;
#pragma unroll
  for (int mi = 0; mi < 4; mi++)
#pragma unroll
    for (int ni = 0; ni < 4; ni++) {
      const int ml = wm * 64 + mi * 16 + quad * 4;
      const int nl = wn * 64 + ni * 16 + l16;
      *(f32x4*)(Cp + (size_t)nl * 128 + ml) = acc[mi][ni];
    }
}

// sum slices, scale, cast bf16, write G + mirror.  Blocks >= 320: meanV part.
__global__ __launch_bounds__(256) void g_fin_kernel(const float* __restrict__ G_part,
                                                    unsigned short* __restrict__ Gb,
                                                    const float* __restrict__ mean_x,
                                                    const float* __restrict__ Wv,
                                                    float* __restrict__ meanV) {
  const int blk = blockIdx.x;  // 4*10*8 + 8
  if (blk >= 320) {
    // meanV[b*512+e] = (1/8192) sum_d mean_x[b*512+d] * Wv[e*512+d]
    const int idx = (blk - 320) * 256 + threadIdx.x;
    const int b = idx >> 9, e = idx & 511;
    const float* mx = mean_x + b * 512;
    const float* wr = Wv + (size_t)e * 512;
    float s = 0.f;
    for (int d = 0; d < 512; d += 4) {
      f32x4 a = *(const f32x4*)(mx + d);
      f32x4 w4 = *(const f32x4*)(wr + d);
      s += a[0] * w4[0] + a[1] * w4[1] + a[2] * w4[2] + a[3] * w4[3];
    }
    meanV[idx] = s * (1.f / 8192.f);
    return;
  }
  const int b = blk / 80, rem = blk % 80;
  const int t = rem >> 3, cc = rem & 7;
  const int i = TI[t], j = TJ[t];
  const int m0 = i * 128, n0 = j * 128;
  const int tid = threadIdx.x;
  const int np = cc * 16 + (tid >> 4);
  const int mp = (tid & 15) * 8;
  f32x4 s0 = f32x4{0.f, 0.f, 0.f, 0.f}, s1 = f32x4{0.f, 0.f, 0.f, 0.f};
#pragma unroll
  for (int s = 0; s < 16; s++) {
    const float* p = G_part + (((size_t)(b * 16 + s)) * 10 + t) * 16384 + (size_t)np * 128 + mp;
    s0 += *(const f32x4*)p;
    s1 += *(const f32x4*)(p + 4);
  }
  const float scale = (float)(1.0 / (8192.0 * 22.627416997969522));
  unsigned short h[8];
#pragma unroll
  for (int r = 0; r < 4; r++) { h[r] = f2bf(s0[r] * scale); h[r + 4] = f2bf(s1[r] * scale); }
  unsigned short* Gbb = Gb + (size_t)b * 262144;
#pragma unroll
  for (int r = 0; r < 8; r++)
    Gbb[(size_t)(m0 + mp + r) * 512 + (n0 + np)] = h[r];
  if (i != j) {
    u16x8 o;
#pragma unroll
    for (int r = 0; r < 8; r++) o[r] = h[r];
    *(u16x8*)(Gbb + (size_t)(n0 + np) * 512 + (m0 + mp)) = o;
  }
}

// small batched GEMM, row-major bf16 C: C[m][n] = sum_k A[m][k]B[n][k], all 512
__global__ __launch_bounds__(256) void gemm_rm_kernel(const unsigned short* __restrict__ A,
                                                      const unsigned short* __restrict__ B,
                                                      unsigned short* __restrict__ C,
                                                      size_t Abs, size_t Bbs) {
  const int b = blockIdx.z;
  const int m0 = blockIdx.x * BM, n0 = blockIdx.y * BN;
  f32x4 acc[4][4];
  gemm_tile(A + (size_t)b * Abs, 512, B + (size_t)b * Bbs, 512, 512, m0, n0, acc, false);
  unsigned short* Cb = C + (size_t)b * 262144;
  const int tid = threadIdx.x, lane = tid & 63, w = tid >> 6;
  const int wm = w >> 1, wn = w & 1, quad = lane >> 4, l16 = lane & 15;
#pragma unroll
  for (int mi = 0; mi < 4; mi++)
#pragma unroll
    for (int ni = 0; ni < 4; ni++) {
      const int m = m0 + wm * 64 + mi * 16 + quad * 4;
      const int n = n0 + wn * 64 + ni * 16 + l16;
#pragma unroll
      for (int r = 0; r < 4; r++)
        Cb[(size_t)(m + r) * 512 + n] = f2bf(acc[mi][ni][r]);
    }
}

// final: out[m][e] = sum_d Xb[m][d]*kvt_b[e][d] + meanV[b][e]
__global__ __launch_bounds__(256) void gemm_out_kernel(
    const unsigned short* __restrict__ Xb, const unsigned short* __restrict__ kvt,
    const float* __restrict__ meanV, float* __restrict__ out) {
  const int m0 = blockIdx.x * BM, n0 = blockIdx.y * BN;
  const int b = blockIdx.x >> 6;
  const unsigned short* Bm = kvt + (size_t)b * 262144;
  f32x4 acc[4][4];
  gemm_tile(Xb, 512, Bm, 512, 512, m0, n0, acc, false);
  const int tid = threadIdx.x, lane = tid & 63, w = tid >> 6;
  const int wm = w >> 1, wn = w & 1, quad = lane >> 4, l16 = lane & 15;
#pragma unroll
  for (int ni = 0; ni < 4; ni++) {
    const int e = n0 + wn * 64 + ni * 16 + l16;
    const float mu = meanV[b * 512 + e];
#pragma unroll
    for (int mi = 0; mi < 4; mi++) {
      const int m = m0 + wm * 64 + mi * 16 + quad * 4;
#pragma unroll
      for (int r = 0; r < 4; r++)
        out[(size_t)(m + r) * 512 + e] = acc[mi][ni][r] + mu;
    }
  }
}

extern "C" void kernel_launch(void* const* d_in, const int* in_sizes, int n_in,
                              void* d_out, int out_size, void* d_ws, size_t ws_size,
                              hipStream_t stream) {
  const float* X = (const float*)d_in[0];
  const float* Wv = (const float*)d_in[1];
  const float* Wth = (const float*)d_in[2];
  float* out = (float*)d_out;
  char* ws = (char*)d_ws;

  unsigned short* Xb = (unsigned short*)(ws);                  // 32 MB
  unsigned short* Xt = (unsigned short*)(ws + 33554432ull);    // 32 MB
  float* G_part = (float*)(ws + 67108864ull);                  // 41.94 MB
  unsigned short* Gb = (unsigned short*)(ws + 109051904ull);   // 2 MB
  unsigned short* Ht = (unsigned short*)(ws + 111149056ull);   // 2 MB
  unsigned short* kvt = (unsigned short*)(ws + 113246208ull);  // 2 MB
  unsigned short* Wvb = (unsigned short*)(ws + 115343360ull);  // 0.5 MB
  unsigned short* Wtb = (unsigned short*)(ws + 115867648ull);  // 0.5 MB
  float* mean_x = (float*)(ws + 116391936ull);                 // 8 KB
  float* meanV = (float*)(ws + 116400128ull);                  // 8 KB

  prep_w_kernel<<<256, 256, 0, stream>>>(Wv, Wth, Wvb, Wtb, mean_x);
  prep_kernel<<<dim3(256, 8), 256, 0, stream>>>(X, Xb, Xt, mean_x);

  g_gemm_kernel<<<dim3(10, 64), 256, 0, stream>>>(Xt, G_part);
  g_fin_kernel<<<328, 256, 0, stream>>>(G_part, Gb, mean_x, Wv, meanV);

  gemm_rm_kernel<<<dim3(4, 4, 4), 256, 0, stream>>>(Wvb, Gb, Ht, 0, 262144);
  gemm_rm_kernel<<<dim3(4, 4, 4), 256, 0, stream>>>(Ht, Wtb, kvt, 262144, 0);

  gemm_out_kernel<<<dim3(256, 4), 256, 0, stream>>>(Xb, kvt, meanV, out);
}

// Round 2
// 237.889 us; speedup vs baseline: 1.0615x; 1.0130x over previous
//
#include <hip/hip_runtime.h>
#include <stdint.h>

// B=4, n=8192, d=512.  Algebraic form:
//   G_b = X_b^T X_b                       [512,512] sym, K=8192
//   kvt_b = Wv * (G_b*scale) * Wth^T      [e][d], scale = 1/(n*sqrt(d))
//   meanV_b[e] = colmean(X_b) . Wv[e][:]
//   out = X_b @ kvt_b(B-layout) + meanV
// Layouts (all K-inner for global_load_lds staging):
//   Xb  [32768][512] bf16        A for final GEMM
//   Xt  [4][512][8192] bf16      A=B for G GEMM (n-inner)
//   Gb  [4][512][512] bf16       scaled, full (mirrored from upper tiles)

typedef __bf16 bf16x8 __attribute__((ext_vector_type(8)));
typedef float f32x4 __attribute__((ext_vector_type(4)));
typedef unsigned short u16x4 __attribute__((ext_vector_type(4)));
typedef unsigned short u16x8 __attribute__((ext_vector_type(8)));

#define BK 32

#define VM0 asm volatile("s_waitcnt vmcnt(0)" ::: "memory")
#define BAR asm volatile("s_barrier" ::: "memory")

template <int N>
__device__ __forceinline__ void vmw() {
  if constexpr (N == 0) asm volatile("s_waitcnt vmcnt(0)" ::: "memory");
  else if constexpr (N == 1) asm volatile("s_waitcnt vmcnt(1)" ::: "memory");
  else if constexpr (N == 2) asm volatile("s_waitcnt vmcnt(2)" ::: "memory");
  else if constexpr (N == 4) asm volatile("s_waitcnt vmcnt(4)" ::: "memory");
  else if constexpr (N == 8) asm volatile("s_waitcnt vmcnt(8)" ::: "memory");
}

__device__ __forceinline__ unsigned short f2bf(float f) {
  union { float f; unsigned int u; } c; c.f = f;
  unsigned int u = c.u;
  return (unsigned short)((u + 0x7FFFu + ((u >> 16) & 1u)) >> 16);  // RNE
}
__device__ __forceinline__ float bf2f(unsigned short h) {
  union { unsigned int u; float f; } c; c.u = ((unsigned int)h) << 16;
  return c.f;
}

__device__ __forceinline__ void gld16(const void* g, void* l) {
  using gptr_t = const __attribute__((address_space(1))) void*;
  using lptr_t = __attribute__((address_space(3))) void*;
  __builtin_amdgcn_global_load_lds((gptr_t)(uintptr_t)g,
                                   (lptr_t)(uint32_t)(uintptr_t)l, 16, 0, 0);
}

// TBxTB tile GEMM core: C[m][n] = sum_k A[m0+m][k] * B[n0+n][k]
// T3-min/T4 pipeline: stage tile t+1 before computing tile t, counted vmcnt
// (never 0 in-loop) so next-tile loads stay in flight across the barrier.
// K must be a multiple of 64. If sameAB, B staging is skipped (B==A tile).
// TB=128: 4-frag waves (heavy kernels).  TB=64: 2-frag, 4x more blocks
// (small 512^3 GEMMs that otherwise leave 3/4 of the chip idle).
template <int TB>
__device__ __forceinline__ void gemm_tile(const unsigned short* __restrict__ A, int lda,
                                          const unsigned short* __restrict__ B, int ldb,
                                          int K, int m0, int n0,
                                          f32x4 (&acc)[TB / 32][TB / 32], bool sameAB) {
  static_assert(TB == 64 || TB == 128, "TB");
  constexpr int FR = TB / 32;    // MFMA frags per wave dim
  constexpr int LPT = TB / 32;   // wait: slots = TB*4, threads = 256 -> TB/64... 
  constexpr int LJ = (TB * 4) / 256;  // 16B loads per thread per matrix
  __shared__ unsigned short sA[2][TB * BK];
  __shared__ unsigned short sB[2][TB * BK];
  const int tid = threadIdx.x;
  const int lane = tid & 63;
  const int w = tid >> 6;
  const int wm = w >> 1, wn = w & 1;
  const int quad = lane >> 4, l16 = lane & 15;

#pragma unroll
  for (int mi = 0; mi < FR; mi++)
#pragma unroll
    for (int ni = 0; ni < FR; ni++) acc[mi][ni] = f32x4{0.f, 0.f, 0.f, 0.f};

  auto stage = [&](int bb, int kk) {
#pragma unroll
    for (int j = 0; j < LJ; j++) {
      const int slot = w * (LJ * 64) + j * 64 + lane;
      const int row = slot >> 2;
      const int col = (slot & 3) * 8;
      const int base = w * (LJ * 64) + j * 64;  // wave-uniform LDS base
      gld16(A + (size_t)(m0 + row) * lda + kk + col, (char*)sA[bb] + (size_t)base * 16);
      if (!sameAB)
        gld16(B + (size_t)(n0 + row) * ldb + kk + col, (char*)sB[bb] + (size_t)base * 16);
    }
  };

  auto compute = [&](int bb) {
    const unsigned short* as = sA[bb];
    const unsigned short* bs = sameAB ? sA[bb] : sB[bb];
    bf16x8 af[FR], bfr[FR];
#pragma unroll
    for (int mi = 0; mi < FR; mi++)
      af[mi] = *(const bf16x8*)&as[(wm * (TB / 2) + mi * 16 + l16) * BK + quad * 8];
#pragma unroll
    for (int ni = 0; ni < FR; ni++)
      bfr[ni] = *(const bf16x8*)&bs[(wn * (TB / 2) + ni * 16 + l16) * BK + quad * 8];
#pragma unroll
    for (int mi = 0; mi < FR; mi++)
#pragma unroll
      for (int ni = 0; ni < FR; ni++)
        acc[mi][ni] = __builtin_amdgcn_mfma_f32_16x16x32_bf16(af[mi], bfr[ni],
                                                              acc[mi][ni], 0, 0, 0);
  };

  stage(0, 0);
  for (int kt = 0; kt < K; kt += 2 * BK) {
    stage(1, kt + BK);
    if (sameAB) { vmw<LJ>(); } else { vmw<2 * LJ>(); }
    BAR;
    compute(0);
    BAR;
    if (kt + 2 * BK < K) {
      stage(0, kt + 2 * BK);
      if (sameAB) { vmw<LJ>(); } else { vmw<2 * LJ>(); }
    } else {
      VM0;
    }
    BAR;
    compute(1);
    BAR;
  }
}

// ---- prep: X fp32 -> Xb bf16 + Xt bf16 (per-batch transpose), fused colsum ----
// 128n x 64d tile per block.  sched_barrier(0) after the load batch forces all
// 8 16B loads in flight before any consumer (round-1 VGPR=32 proved the
// compiler chunked them -> serial HBM round trips).  bf16 conversion done once
// and reused for Xb + Xt + colsum.  Xb stores moved past the barrier so the
// syncthreads vmcnt(0) drain doesn't serialize on them.
__global__ __launch_bounds__(256) void prep_kernel(const float* __restrict__ X,
                                                   unsigned short* __restrict__ Xb,
                                                   unsigned short* __restrict__ Xt,
                                                   float* __restrict__ mean_x) {
  __shared__ unsigned short sT[2][64 * 64];
  const int t = threadIdx.x;
  const int n0 = blockIdx.x * 128, d0 = blockIdx.y * 64;
  const int b = n0 >> 13, nb = n0 & 8191;
  const int r0 = (t >> 4) * 4, c0 = (t & 15) * 4;
  f32x4 v[2][4];
#pragma unroll
  for (int s = 0; s < 2; s++)
#pragma unroll
    for (int i = 0; i < 4; i++)
      v[s][i] = *(const f32x4*)(X + (size_t)(n0 + s * 64 + r0 + i) * 512 + d0 + c0);
  __builtin_amdgcn_sched_barrier(0);  // all 8 loads issued before any use
  // convert once, reuse for Xb + Xt + colsum
  u16x4 o[2][4];
#pragma unroll
  for (int s = 0; s < 2; s++)
#pragma unroll
    for (int i = 0; i < 4; i++)
#pragma unroll
      for (int j = 0; j < 4; j++) o[s][i][j] = f2bf(v[s][i][j]);
  // transposed into LDS, XOR swizzle in 8-elem blocks (keeps u16x8 reads aligned)
#pragma unroll
  for (int s = 0; s < 2; s++)
#pragma unroll
    for (int j = 0; j < 4; j++) {
      u16x4 wv;
#pragma unroll
      for (int i = 0; i < 4; i++) wv[i] = o[s][i][j];
      const int c = c0 + j;
      const int rsw = r0 ^ (c & 0x38);
      *(u16x4*)&sT[s][c * 64 + rsw] = wv;
    }
  __syncthreads();
  // Xb (row-major cast), coalesced 8B stores — after barrier, fire-and-forget
#pragma unroll
  for (int s = 0; s < 2; s++)
#pragma unroll
    for (int i = 0; i < 4; i++)
      *(u16x4*)(Xb + (size_t)(n0 + s * 64 + r0 + i) * 512 + d0 + c0) = o[s][i];
  // Xt stores: thread t -> cols c, c+32 (d-index), 8 n-elems each subtile, 16B stores
  const int cr = t >> 3, p = t & 7;
  float csum[2] = {0.f, 0.f};
#pragma unroll
  for (int s = 0; s < 2; s++)
#pragma unroll
    for (int h = 0; h < 2; h++) {
      const int c = cr + h * 32;
      const int phys = (p * 8) ^ (c & 0x38);
      u16x8 val = *(const u16x8*)&sT[s][c * 64 + phys];
      *(u16x8*)(Xt + (size_t)(b * 512 + d0 + c) * 8192 + nb + s * 64 + p * 8) = val;
      float ss = 0.f;
#pragma unroll
      for (int j = 0; j < 8; j++) ss += bf2f(val[j]);
      csum[h] += ss;
    }
  // reduce over the 8 p-threads of each (cr,h), one atomic per column
#pragma unroll
  for (int h = 0; h < 2; h++) {
    float sv = csum[h];
    sv += __shfl_xor(sv, 1);
    sv += __shfl_xor(sv, 2);
    sv += __shfl_xor(sv, 4);
    if (p == 0) atomicAdd(&mean_x[b * 512 + d0 + cr + h * 32], sv);
  }
}

// ---- W casts + zero-init of mean_x (runs before prep in-stream) ----
__global__ __launch_bounds__(256) void prep_w_kernel(const float* __restrict__ Wv,
                                                     const float* __restrict__ Wth,
                                                     unsigned short* __restrict__ Wvb,
                                                     unsigned short* __restrict__ Wtb,
                                                     float* __restrict__ mean_x) {
  const int blk = blockIdx.x;
  const int t = threadIdx.x;
  if (blk == 0) {
#pragma unroll
    for (int i = 0; i < 8; i++) mean_x[t + i * 256] = 0.f;
  }
  const float* src = (blk < 128) ? Wv : Wth;
  unsigned short* dst = (blk < 128) ? Wvb : Wtb;
  const int i = (blk & 127) * 256 + t;
  const f32x4* pp = (const f32x4*)(src + (size_t)i * 8);
  f32x4 v0 = pp[0], v1 = pp[1];
  u16x8 o;
  o[0] = f2bf(v0[0]); o[1] = f2bf(v0[1]); o[2] = f2bf(v0[2]); o[3] = f2bf(v0[3]);
  o[4] = f2bf(v1[0]); o[5] = f2bf(v1[1]); o[6] = f2bf(v1[2]); o[7] = f2bf(v1[3]);
  *(u16x8*)(dst + (size_t)i * 8) = o;
}

// ---- G = Xt Xt^T (per batch), split-K=16, upper tiles only ----
static __device__ const int TI[10] = {0, 0, 0, 0, 1, 1, 1, 2, 2, 3};
static __device__ const int TJ[10] = {0, 1, 2, 3, 1, 2, 3, 2, 3, 3};

__global__ __launch_bounds__(256) void g_gemm_kernel(const unsigned short* __restrict__ Xt,
                                                     float* __restrict__ G_part) {
  const int t = blockIdx.x;        // 0..9 upper tile
  const int z = blockIdx.y;        // b*16 + s
  const int b = z >> 4, s = z & 15;
  const int m0 = TI[t] * 128, n0 = TJ[t] * 128;
  const unsigned short* A = Xt + (size_t)b * 512 * 8192 + (size_t)s * 512;
  f32x4 acc[4][4];
  gemm_tile<128>(A, 8192, A, 8192, 512, m0, n0, acc, m0 == n0);
  float* Cp = G_part + ((size_t)z * 10 + t) * 16384;  // tile stored [n_local][m_local]
  const int tid = threadIdx.x, lane = tid & 63, w = tid >> 6;
  const int wm = w >> 1, wn = w & 1, quad = lane >> 4, l16 = lane & 15;
#pragma unroll
  for (int mi = 0; mi < 4; mi++)
#pragma unroll
    for (int ni = 0; ni < 4; ni++) {
      const int ml = wm * 64 + mi * 16 + quad * 4;
      const int nl = wn * 64 + ni * 16 + l16;
      *(f32x4*)(Cp + (size_t)nl * 128 + ml) = acc[mi][ni];
    }
}

// sum slices, scale, cast bf16, write G + mirror.  Blocks >= 320: meanV part.
__global__ __launch_bounds__(256) void g_fin_kernel(const float* __restrict__ G_part,
                                                    unsigned short* __restrict__ Gb,
                                                    const float* __restrict__ mean_x,
                                                    const float* __restrict__ Wv,
                                                    float* __restrict__ meanV) {
  const int blk = blockIdx.x;  // 4*10*8 + 8
  if (blk >= 320) {
    // meanV[b*512+e] = (1/8192) sum_d mean_x[b*512+d] * Wv[e*512+d]
    const int idx = (blk - 320) * 256 + threadIdx.x;
    const int b = idx >> 9, e = idx & 511;
    const float* mx = mean_x + b * 512;
    const float* wr = Wv + (size_t)e * 512;
    float s = 0.f;
    for (int d = 0; d < 512; d += 4) {
      f32x4 a = *(const f32x4*)(mx + d);
      f32x4 w4 = *(const f32x4*)(wr + d);
      s += a[0] * w4[0] + a[1] * w4[1] + a[2] * w4[2] + a[3] * w4[3];
    }
    meanV[idx] = s * (1.f / 8192.f);
    return;
  }
  const int b = blk / 80, rem = blk % 80;
  const int t = rem >> 3, cc = rem & 7;
  const int i = TI[t], j = TJ[t];
  const int m0 = i * 128, n0 = j * 128;
  const int tid = threadIdx.x;
  const int np = cc * 16 + (tid >> 4);
  const int mp = (tid & 15) * 8;
  f32x4 s0 = f32x4{0.f, 0.f, 0.f, 0.f}, s1 = f32x4{0.f, 0.f, 0.f, 0.f};
#pragma unroll
  for (int s = 0; s < 16; s++) {
    const float* p = G_part + (((size_t)(b * 16 + s)) * 10 + t) * 16384 + (size_t)np * 128 + mp;
    s0 += *(const f32x4*)p;
    s1 += *(const f32x4*)(p + 4);
  }
  const float scale = (float)(1.0 / (8192.0 * 22.627416997969522));
  unsigned short h[8];
#pragma unroll
  for (int r = 0; r < 4; r++) { h[r] = f2bf(s0[r] * scale); h[r + 4] = f2bf(s1[r] * scale); }
  unsigned short* Gbb = Gb + (size_t)b * 262144;
#pragma unroll
  for (int r = 0; r < 8; r++)
    Gbb[(size_t)(m0 + mp + r) * 512 + (n0 + np)] = h[r];
  if (i != j) {
    u16x8 o;
#pragma unroll
    for (int r = 0; r < 8; r++) o[r] = h[r];
    *(u16x8*)(Gbb + (size_t)(n0 + np) * 512 + (m0 + mp)) = o;
  }
}

// small batched GEMM, row-major bf16 C: C[m][n] = sum_k A[m][k]B[n][k], all 512.
// TB=64 tiles: 256 blocks instead of 64 -> whole chip busy.
__global__ __launch_bounds__(256) void gemm_rm_kernel(const unsigned short* __restrict__ A,
                                                      const unsigned short* __restrict__ B,
                                                      unsigned short* __restrict__ C,
                                                      size_t Abs, size_t Bbs) {
  const int b = blockIdx.z;
  const int m0 = blockIdx.x * 64, n0 = blockIdx.y * 64;
  f32x4 acc[2][2];
  gemm_tile<64>(A + (size_t)b * Abs, 512, B + (size_t)b * Bbs, 512, 512, m0, n0, acc, false);
  unsigned short* Cb = C + (size_t)b * 262144;
  const int tid = threadIdx.x, lane = tid & 63, w = tid >> 6;
  const int wm = w >> 1, wn = w & 1, quad = lane >> 4, l16 = lane & 15;
#pragma unroll
  for (int mi = 0; mi < 2; mi++)
#pragma unroll
    for (int ni = 0; ni < 2; ni++) {
      const int m = m0 + wm * 32 + mi * 16 + quad * 4;
      const int n = n0 + wn * 32 + ni * 16 + l16;
#pragma unroll
      for (int r = 0; r < 4; r++)
        Cb[(size_t)(m + r) * 512 + n] = f2bf(acc[mi][ni][r]);
    }
}

// final: out[m][e] = sum_d Xb[m][d]*kvt_b[e][d] + meanV[b][e]
__global__ __launch_bounds__(256) void gemm_out_kernel(
    const unsigned short* __restrict__ Xb, const unsigned short* __restrict__ kvt,
    const float* __restrict__ meanV, float* __restrict__ out) {
  const int m0 = blockIdx.x * 128, n0 = blockIdx.y * 128;
  const int b = blockIdx.x >> 6;
  const unsigned short* Bm = kvt + (size_t)b * 262144;
  f32x4 acc[4][4];
  gemm_tile<128>(Xb, 512, Bm, 512, 512, m0, n0, acc, false);
  const int tid = threadIdx.x, lane = tid & 63, w = tid >> 6;
  const int wm = w >> 1, wn = w & 1, quad = lane >> 4, l16 = lane & 15;
#pragma unroll
  for (int ni = 0; ni < 4; ni++) {
    const int e = n0 + wn * 64 + ni * 16 + l16;
    const float mu = meanV[b * 512 + e];
#pragma unroll
    for (int mi = 0; mi < 4; mi++) {
      const int m = m0 + wm * 64 + mi * 16 + quad * 4;
#pragma unroll
      for (int r = 0; r < 4; r++)
        out[(size_t)(m + r) * 512 + e] = acc[mi][ni][r] + mu;
    }
  }
}

extern "C" void kernel_launch(void* const* d_in, const int* in_sizes, int n_in,
                              void* d_out, int out_size, void* d_ws, size_t ws_size,
                              hipStream_t stream) {
  const float* X = (const float*)d_in[0];
  const float* Wv = (const float*)d_in[1];
  const float* Wth = (const float*)d_in[2];
  float* out = (float*)d_out;
  char* ws = (char*)d_ws;

  unsigned short* Xb = (unsigned short*)(ws);                  // 32 MB
  unsigned short* Xt = (unsigned short*)(ws + 33554432ull);    // 32 MB
  float* G_part = (float*)(ws + 67108864ull);                  // 41.94 MB
  unsigned short* Gb = (unsigned short*)(ws + 109051904ull);   // 2 MB
  unsigned short* Ht = (unsigned short*)(ws + 111149056ull);   // 2 MB
  unsigned short* kvt = (unsigned short*)(ws + 113246208ull);  // 2 MB
  unsigned short* Wvb = (unsigned short*)(ws + 115343360ull);  // 0.5 MB
  unsigned short* Wtb = (unsigned short*)(ws + 115867648ull);  // 0.5 MB
  float* mean_x = (float*)(ws + 116391936ull);                 // 8 KB
  float* meanV = (float*)(ws + 116400128ull);                  // 8 KB

  prep_w_kernel<<<256, 256, 0, stream>>>(Wv, Wth, Wvb, Wtb, mean_x);
  prep_kernel<<<dim3(256, 8), 256, 0, stream>>>(X, Xb, Xt, mean_x);

  g_gemm_kernel<<<dim3(10, 64), 256, 0, stream>>>(Xt, G_part);
  g_fin_kernel<<<328, 256, 0, stream>>>(G_part, Gb, mean_x, Wv, meanV);

  gemm_rm_kernel<<<dim3(8, 8, 4), 256, 0, stream>>>(Wvb, Gb, Ht, 0, 262144);
  gemm_rm_kernel<<<dim3(8, 8, 4), 256, 0, stream>>>(Ht, Wtb, kvt, 262144, 0);

  gemm_out_kernel<<<dim3(256, 4), 256, 0, stream>>>(Xb, kvt, meanV, out);
}

// Round 3
// 235.113 us; speedup vs baseline: 1.0740x; 1.0118x over previous
//
#include <hip/hip_runtime.h>
#include <stdint.h>

// B=4, n=8192, d=512.  Algebraic form:
//   G_b = X_b^T X_b                       [512,512] sym, K=8192
//   kvt_b = Wv * (G_b*scale) * Wth^T      [e][d], scale = 1/(n*sqrt(d))
//   meanV_b[e] = colmean(X_b) . Wv[e][:]
//   out = X_b @ kvt_b(B-layout) + meanV
// Layouts (all K-inner for global_load_lds staging):
//   Xb  [32768][512] bf16        A for final GEMM
//   Xt  [4][512][8192] bf16      A=B for G GEMM (n-inner)
//   Gb  [4][512][512] bf16       scaled, full (mirrored from upper tiles)

typedef __bf16 bf16x8 __attribute__((ext_vector_type(8)));
typedef float f32x4 __attribute__((ext_vector_type(4)));
typedef unsigned short u16x4 __attribute__((ext_vector_type(4)));
typedef unsigned short u16x8 __attribute__((ext_vector_type(8)));

#define BK 32

#define BAR asm volatile("s_barrier" ::: "memory")

template <int N>
__device__ __forceinline__ void vmw() {
  static_assert(N == 0 || N == 1 || N == 2 || N == 4 || N == 8, "vmw");
  if constexpr (N == 0) asm volatile("s_waitcnt vmcnt(0)" ::: "memory");
  else if constexpr (N == 1) asm volatile("s_waitcnt vmcnt(1)" ::: "memory");
  else if constexpr (N == 2) asm volatile("s_waitcnt vmcnt(2)" ::: "memory");
  else if constexpr (N == 4) asm volatile("s_waitcnt vmcnt(4)" ::: "memory");
  else if constexpr (N == 8) asm volatile("s_waitcnt vmcnt(8)" ::: "memory");
}

__device__ __forceinline__ unsigned short f2bf(float f) {
  union { float f; unsigned int u; } c; c.f = f;
  unsigned int u = c.u;
  return (unsigned short)((u + 0x7FFFu + ((u >> 16) & 1u)) >> 16);  // RNE
}
__device__ __forceinline__ float bf2f(unsigned short h) {
  union { unsigned int u; float f; } c; c.u = ((unsigned int)h) << 16;
  return c.f;
}

__device__ __forceinline__ void gld16(const void* g, void* l) {
  using gptr_t = const __attribute__((address_space(1))) void*;
  using lptr_t = __attribute__((address_space(3))) void*;
  __builtin_amdgcn_global_load_lds((gptr_t)(uintptr_t)g,
                                   (lptr_t)(uint32_t)(uintptr_t)l, 16, 0, 0);
}

// TBxTB tile GEMM core, K fixed = 512: C[m][n] = sum_k A[m0+m][k] * B[n0+n][k]
// 3-buffer pipeline, 2 stages in flight across barriers (counted vmcnt, never 0
// until the tail).  16-B granule XOR swizzle kills the 8-way ds_read_b128 bank
// conflict of the [row][32] bf16 layout: physical granule = 4*row + (q ^
// ((row>>1)&3)); staging pre-swizzles the GLOBAL source column (LDS dest of
// global_load_lds must stay linear), the ds_read applies the same XOR.
template <int TB, bool SAME>
__device__ __forceinline__ void gemm_tile(const unsigned short* __restrict__ A, int lda,
                                          const unsigned short* __restrict__ B, int ldb,
                                          int m0, int n0, f32x4 (&acc)[TB / 32][TB / 32]) {
  static_assert(TB == 64 || TB == 128, "TB");
  constexpr int FR = TB / 32;         // MFMA frags per wave dim
  constexpr int LJ = (TB * 4) / 256;  // 16B loads per thread per matrix per stage
  constexpr int LPS = SAME ? LJ : 2 * LJ;  // loads in flight per stage
  constexpr int NK = 512 / BK;        // 16 K-steps
  __shared__ unsigned short sA[3][TB * BK];
  __shared__ unsigned short sB[3][TB * BK];
  const int tid = threadIdx.x;
  const int lane = tid & 63;
  const int w = tid >> 6;
  const int wm = w >> 1, wn = w & 1;
  const int quad = lane >> 4, l16 = lane & 15;
  const int sq = (quad ^ ((l16 >> 1) & 3)) * 8;  // swizzled k-granule (elems)

#pragma unroll
  for (int mi = 0; mi < FR; mi++)
#pragma unroll
    for (int ni = 0; ni < FR; ni++) acc[mi][ni] = f32x4{0.f, 0.f, 0.f, 0.f};

  auto stage = [&](int bb, int kt) {
    const int kk = kt * BK;
#pragma unroll
    for (int j = 0; j < LJ; j++) {
      const int slot = w * (LJ * 64) + j * 64 + lane;  // physical 16B granule
      const int row = slot >> 2;
      const int col = ((slot & 3) ^ ((slot >> 3) & 3)) * 8;  // pre-swizzled src
      const int basegr = w * (LJ * 64) + j * 64;  // wave-uniform LDS base
      gld16(A + (size_t)(m0 + row) * lda + kk + col, (char*)sA[bb] + (size_t)basegr * 16);
      if constexpr (!SAME)
        gld16(B + (size_t)(n0 + row) * ldb + kk + col, (char*)sB[bb] + (size_t)basegr * 16);
    }
  };

  auto compute = [&](int bb) {
    const unsigned short* as = sA[bb];
    const unsigned short* bs = SAME ? sA[bb] : sB[bb];
    bf16x8 af[FR], bfr[FR];
#pragma unroll
    for (int mi = 0; mi < FR; mi++)
      af[mi] = *(const bf16x8*)&as[(wm * (TB / 2) + mi * 16 + l16) * BK + sq];
#pragma unroll
    for (int ni = 0; ni < FR; ni++)
      bfr[ni] = *(const bf16x8*)&bs[(wn * (TB / 2) + ni * 16 + l16) * BK + sq];
#pragma unroll
    for (int mi = 0; mi < FR; mi++)
#pragma unroll
      for (int ni = 0; ni < FR; ni++)
        acc[mi][ni] = __builtin_amdgcn_mfma_f32_16x16x32_bf16(af[mi], bfr[ni],
                                                              acc[mi][ni], 0, 0, 0);
  };

  stage(0, 0);
  stage(1, 1);
  stage(2, 2);
#pragma unroll
  for (int kt = 0; kt < NK; ++kt) {
    if (kt < NK - 2) { vmw<2 * LPS>(); }       // stage kt done, 2 in flight
    else if (kt == NK - 2) { vmw<LPS>(); }
    else { vmw<0>(); }
    BAR;
    compute(kt % 3);
    BAR;
    if (kt < NK - 3) stage(kt % 3, kt + 3);
  }
}

// ---- prep: X fp32 -> Xb bf16 + Xt bf16 (per-batch transpose), fused colsum ----
// 128n x 64d tile per block.  sched_barrier(0) after the load batch forces all
// 8 16B loads in flight before any consumer (round-1 VGPR=32 proved the
// compiler chunked them -> serial HBM round trips).  bf16 conversion done once
// and reused for Xb + Xt + colsum.  Xb stores moved past the barrier so the
// syncthreads vmcnt(0) drain doesn't serialize on them.
__global__ __launch_bounds__(256) void prep_kernel(const float* __restrict__ X,
                                                   unsigned short* __restrict__ Xb,
                                                   unsigned short* __restrict__ Xt,
                                                   float* __restrict__ mean_x) {
  __shared__ unsigned short sT[2][64 * 64];
  const int t = threadIdx.x;
  const int n0 = blockIdx.x * 128, d0 = blockIdx.y * 64;
  const int b = n0 >> 13, nb = n0 & 8191;
  const int r0 = (t >> 4) * 4, c0 = (t & 15) * 4;
  f32x4 v[2][4];
#pragma unroll
  for (int s = 0; s < 2; s++)
#pragma unroll
    for (int i = 0; i < 4; i++)
      v[s][i] = *(const f32x4*)(X + (size_t)(n0 + s * 64 + r0 + i) * 512 + d0 + c0);
  __builtin_amdgcn_sched_barrier(0);  // all 8 loads issued before any use
  // convert once, reuse for Xb + Xt + colsum
  u16x4 o[2][4];
#pragma unroll
  for (int s = 0; s < 2; s++)
#pragma unroll
    for (int i = 0; i < 4; i++)
#pragma unroll
      for (int j = 0; j < 4; j++) o[s][i][j] = f2bf(v[s][i][j]);
  // transposed into LDS, XOR swizzle in 8-elem blocks (keeps u16x8 reads aligned)
#pragma unroll
  for (int s = 0; s < 2; s++)
#pragma unroll
    for (int j = 0; j < 4; j++) {
      u16x4 wv;
#pragma unroll
      for (int i = 0; i < 4; i++) wv[i] = o[s][i][j];
      const int c = c0 + j;
      const int rsw = r0 ^ (c & 0x38);
      *(u16x4*)&sT[s][c * 64 + rsw] = wv;
    }
  __syncthreads();
  // Xb (row-major cast), coalesced 8B stores — after barrier, fire-and-forget
#pragma unroll
  for (int s = 0; s < 2; s++)
#pragma unroll
    for (int i = 0; i < 4; i++)
      *(u16x4*)(Xb + (size_t)(n0 + s * 64 + r0 + i) * 512 + d0 + c0) = o[s][i];
  // Xt stores: thread t -> cols c, c+32 (d-index), 8 n-elems each subtile, 16B stores
  const int cr = t >> 3, p = t & 7;
  float csum[2] = {0.f, 0.f};
#pragma unroll
  for (int s = 0; s < 2; s++)
#pragma unroll
    for (int h = 0; h < 2; h++) {
      const int c = cr + h * 32;
      const int phys = (p * 8) ^ (c & 0x38);
      u16x8 val = *(const u16x8*)&sT[s][c * 64 + phys];
      *(u16x8*)(Xt + (size_t)(b * 512 + d0 + c) * 8192 + nb + s * 64 + p * 8) = val;
      float ss = 0.f;
#pragma unroll
      for (int j = 0; j < 8; j++) ss += bf2f(val[j]);
      csum[h] += ss;
    }
  // reduce over the 8 p-threads of each (cr,h), one atomic per column
#pragma unroll
  for (int h = 0; h < 2; h++) {
    float sv = csum[h];
    sv += __shfl_xor(sv, 1);
    sv += __shfl_xor(sv, 2);
    sv += __shfl_xor(sv, 4);
    if (p == 0) atomicAdd(&mean_x[b * 512 + d0 + cr + h * 32], sv);
  }
}

// ---- W casts + zero-init of mean_x (runs before prep in-stream) ----
__global__ __launch_bounds__(256) void prep_w_kernel(const float* __restrict__ Wv,
                                                     const float* __restrict__ Wth,
                                                     unsigned short* __restrict__ Wvb,
                                                     unsigned short* __restrict__ Wtb,
                                                     float* __restrict__ mean_x) {
  const int blk = blockIdx.x;
  const int t = threadIdx.x;
  if (blk == 0) {
#pragma unroll
    for (int i = 0; i < 8; i++) mean_x[t + i * 256] = 0.f;
  }
  const float* src = (blk < 128) ? Wv : Wth;
  unsigned short* dst = (blk < 128) ? Wvb : Wtb;
  const int i = (blk & 127) * 256 + t;
  const f32x4* pp = (const f32x4*)(src + (size_t)i * 8);
  f32x4 v0 = pp[0], v1 = pp[1];
  u16x8 o;
  o[0] = f2bf(v0[0]); o[1] = f2bf(v0[1]); o[2] = f2bf(v0[2]); o[3] = f2bf(v0[3]);
  o[4] = f2bf(v1[0]); o[5] = f2bf(v1[1]); o[6] = f2bf(v1[2]); o[7] = f2bf(v1[3]);
  *(u16x8*)(dst + (size_t)i * 8) = o;
}

// ---- G = Xt Xt^T (per batch), split-K=16, upper tiles only ----
static __device__ const int TI[10] = {0, 0, 0, 0, 1, 1, 1, 2, 2, 3};
static __device__ const int TJ[10] = {0, 1, 2, 3, 1, 2, 3, 2, 3, 3};

__global__ __launch_bounds__(256) void g_gemm_kernel(const unsigned short* __restrict__ Xt,
                                                     float* __restrict__ G_part) {
  const int t = blockIdx.x;        // 0..9 upper tile
  const int z = blockIdx.y;        // b*16 + s
  const int b = z >> 4, s = z & 15;
  const int m0 = TI[t] * 128, n0 = TJ[t] * 128;
  const unsigned short* A = Xt + (size_t)b * 512 * 8192 + (size_t)s * 512;
  f32x4 acc[4][4];
  if (m0 == n0)
    gemm_tile<128, true>(A, 8192, A, 8192, m0, n0, acc);
  else
    gemm_tile<128, false>(A, 8192, A, 8192, m0, n0, acc);
  float* Cp = G_part + ((size_t)z * 10 + t) * 16384;  // tile stored [n_local][m_local]
  const int tid = threadIdx.x, lane = tid & 63, w = tid >> 6;
  const int wm = w >> 1, wn = w & 1, quad = lane >> 4, l16 = lane & 15;
#pragma unroll
  for (int mi = 0; mi < 4; mi++)
#pragma unroll
    for (int ni = 0; ni < 4; ni++) {
      const int ml = wm * 64 + mi * 16 + quad * 4;
      const int nl = wn * 64 + ni * 16 + l16;
      *(f32x4*)(Cp + (size_t)nl * 128 + ml) = acc[mi][ni];
    }
}

// sum slices, scale, cast bf16, write G + mirror.  Blocks >= 320: meanV part.
__global__ __launch_bounds__(256) void g_fin_kernel(const float* __restrict__ G_part,
                                                    unsigned short* __restrict__ Gb,
                                                    const float* __restrict__ mean_x,
                                                    const float* __restrict__ Wv,
                                                    float* __restrict__ meanV) {
  const int blk = blockIdx.x;  // 4*10*8 + 8
  if (blk >= 320) {
    // meanV[b*512+e] = (1/8192) sum_d mean_x[b*512+d] * Wv[e*512+d]
    const int idx = (blk - 320) * 256 + threadIdx.x;
    const int b = idx >> 9, e = idx & 511;
    const float* mx = mean_x + b * 512;
    const float* wr = Wv + (size_t)e * 512;
    float s = 0.f;
    for (int d = 0; d < 512; d += 4) {
      f32x4 a = *(const f32x4*)(mx + d);
      f32x4 w4 = *(const f32x4*)(wr + d);
      s += a[0] * w4[0] + a[1] * w4[1] + a[2] * w4[2] + a[3] * w4[3];
    }
    meanV[idx] = s * (1.f / 8192.f);
    return;
  }
  const int b = blk / 80, rem = blk % 80;
  const int t = rem >> 3, cc = rem & 7;
  const int i = TI[t], j = TJ[t];
  const int m0 = i * 128, n0 = j * 128;
  const int tid = threadIdx.x;
  const int np = cc * 16 + (tid >> 4);
  const int mp = (tid & 15) * 8;
  f32x4 s0 = f32x4{0.f, 0.f, 0.f, 0.f}, s1 = f32x4{0.f, 0.f, 0.f, 0.f};
#pragma unroll
  for (int s = 0; s < 16; s++) {
    const float* p = G_part + (((size_t)(b * 16 + s)) * 10 + t) * 16384 + (size_t)np * 128 + mp;
    s0 += *(const f32x4*)p;
    s1 += *(const f32x4*)(p + 4);
  }
  const float scale = (float)(1.0 / (8192.0 * 22.627416997969522));
  unsigned short h[8];
#pragma unroll
  for (int r = 0; r < 4; r++) { h[r] = f2bf(s0[r] * scale); h[r + 4] = f2bf(s1[r] * scale); }
  unsigned short* Gbb = Gb + (size_t)b * 262144;
#pragma unroll
  for (int r = 0; r < 8; r++)
    Gbb[(size_t)(m0 + mp + r) * 512 + (n0 + np)] = h[r];
  if (i != j) {
    u16x8 o;
#pragma unroll
    for (int r = 0; r < 8; r++) o[r] = h[r];
    *(u16x8*)(Gbb + (size_t)(n0 + np) * 512 + (m0 + mp)) = o;
  }
}

// small batched GEMM, row-major bf16 C: C[m][n] = sum_k A[m][k]B[n][k], all 512.
// TB=64 tiles: 256 blocks instead of 64 -> whole chip busy.
__global__ __launch_bounds__(256) void gemm_rm_kernel(const unsigned short* __restrict__ A,
                                                      const unsigned short* __restrict__ B,
                                                      unsigned short* __restrict__ C,
                                                      size_t Abs, size_t Bbs) {
  const int b = blockIdx.z;
  const int m0 = blockIdx.x * 64, n0 = blockIdx.y * 64;
  f32x4 acc[2][2];
  gemm_tile<64, false>(A + (size_t)b * Abs, 512, B + (size_t)b * Bbs, 512, m0, n0, acc);
  unsigned short* Cb = C + (size_t)b * 262144;
  const int tid = threadIdx.x, lane = tid & 63, w = tid >> 6;
  const int wm = w >> 1, wn = w & 1, quad = lane >> 4, l16 = lane & 15;
#pragma unroll
  for (int mi = 0; mi < 2; mi++)
#pragma unroll
    for (int ni = 0; ni < 2; ni++) {
      const int m = m0 + wm * 32 + mi * 16 + quad * 4;
      const int n = n0 + wn * 32 + ni * 16 + l16;
#pragma unroll
      for (int r = 0; r < 4; r++)
        Cb[(size_t)(m + r) * 512 + n] = f2bf(acc[mi][ni][r]);
    }
}

// final: out[m][e] = sum_d Xb[m][d]*kvt_b[e][d] + meanV[b][e]
__global__ __launch_bounds__(256) void gemm_out_kernel(
    const unsigned short* __restrict__ Xb, const unsigned short* __restrict__ kvt,
    const float* __restrict__ meanV, float* __restrict__ out) {
  const int m0 = blockIdx.x * 128, n0 = blockIdx.y * 128;
  const int b = blockIdx.x >> 6;
  const unsigned short* Bm = kvt + (size_t)b * 262144;
  f32x4 acc[4][4];
  gemm_tile<128, false>(Xb, 512, Bm, 512, m0, n0, acc);
  const int tid = threadIdx.x, lane = tid & 63, w = tid >> 6;
  const int wm = w >> 1, wn = w & 1, quad = lane >> 4, l16 = lane & 15;
#pragma unroll
  for (int ni = 0; ni < 4; ni++) {
    const int e = n0 + wn * 64 + ni * 16 + l16;
    const float mu = meanV[b * 512 + e];
#pragma unroll
    for (int mi = 0; mi < 4; mi++) {
      const int m = m0 + wm * 64 + mi * 16 + quad * 4;
#pragma unroll
      for (int r = 0; r < 4; r++)
        out[(size_t)(m + r) * 512 + e] = acc[mi][ni][r] + mu;
    }
  }
}

extern "C" void kernel_launch(void* const* d_in, const int* in_sizes, int n_in,
                              void* d_out, int out_size, void* d_ws, size_t ws_size,
                              hipStream_t stream) {
  const float* X = (const float*)d_in[0];
  const float* Wv = (const float*)d_in[1];
  const float* Wth = (const float*)d_in[2];
  float* out = (float*)d_out;
  char* ws = (char*)d_ws;

  unsigned short* Xb = (unsigned short*)(ws);                  // 32 MB
  unsigned short* Xt = (unsigned short*)(ws + 33554432ull);    // 32 MB
  float* G_part = (float*)(ws + 67108864ull);                  // 41.94 MB
  unsigned short* Gb = (unsigned short*)(ws + 109051904ull);   // 2 MB
  unsigned short* Ht = (unsigned short*)(ws + 111149056ull);   // 2 MB
  unsigned short* kvt = (unsigned short*)(ws + 113246208ull);  // 2 MB
  unsigned short* Wvb = (unsigned short*)(ws + 115343360ull);  // 0.5 MB
  unsigned short* Wtb = (unsigned short*)(ws + 115867648ull);  // 0.5 MB
  float* mean_x = (float*)(ws + 116391936ull);                 // 8 KB
  float* meanV = (float*)(ws + 116400128ull);                  // 8 KB

  prep_w_kernel<<<256, 256, 0, stream>>>(Wv, Wth, Wvb, Wtb, mean_x);
  prep_kernel<<<dim3(256, 8), 256, 0, stream>>>(X, Xb, Xt, mean_x);

  g_gemm_kernel<<<dim3(10, 64), 256, 0, stream>>>(Xt, G_part);
  g_fin_kernel<<<328, 256, 0, stream>>>(G_part, Gb, mean_x, Wv, meanV);

  gemm_rm_kernel<<<dim3(8, 8, 4), 256, 0, stream>>>(Wvb, Gb, Ht, 0, 262144);
  gemm_rm_kernel<<<dim3(8, 8, 4), 256, 0, stream>>>(Ht, Wtb, kvt, 262144, 0);

  gemm_out_kernel<<<dim3(256, 4), 256, 0, stream>>>(Xb, kvt, meanV, out);
}

// Round 5
// 216.064 us; speedup vs baseline: 1.1687x; 1.0882x over previous
//
#include <hip/hip_runtime.h>
#include <stdint.h>

// B=4, n=8192, d=512.  Algebraic form:
//   G_b = X_b^T X_b                       [512,512] sym, K=8192
//   kvt_b = Wv * (G_b*scale) * Wth^T      [e][d], scale = 1/(n*sqrt(d))
//   meanV_b[e] = colmean(X_b) . Wv[e][:]
//   out = X_b @ kvt_b(B-layout) + meanV
// Layouts (all K-inner for global_load_lds staging):
//   Xb  [32768][512] bf16        A for final GEMM
//   Xt  [4][512][8192] bf16      A=B for G GEMM (n-inner, n PERMUTED per 64-blk:
//                                 pos q*8+i holds source n q+8i — G/mean are
//                                 n-permutation-invariant, all d rows identical)
//   Gb  [4][512][512] bf16       scaled, full (mirrored from upper tiles)

typedef __bf16 bf16x8 __attribute__((ext_vector_type(8)));
typedef float f32x4 __attribute__((ext_vector_type(4)));
typedef unsigned short u16x4 __attribute__((ext_vector_type(4)));
typedef unsigned short u16x8 __attribute__((ext_vector_type(8)));

#define BK 32

#define BAR asm volatile("s_barrier" ::: "memory")

template <int N>
__device__ __forceinline__ void vmw() {
  static_assert(N == 0 || N == 1 || N == 2 || N == 4 || N == 8, "vmw");
  if constexpr (N == 0) asm volatile("s_waitcnt vmcnt(0)" ::: "memory");
  else if constexpr (N == 1) asm volatile("s_waitcnt vmcnt(1)" ::: "memory");
  else if constexpr (N == 2) asm volatile("s_waitcnt vmcnt(2)" ::: "memory");
  else if constexpr (N == 4) asm volatile("s_waitcnt vmcnt(4)" ::: "memory");
  else if constexpr (N == 8) asm volatile("s_waitcnt vmcnt(8)" ::: "memory");
}

__device__ __forceinline__ unsigned short f2bf(float f) {
  union { float f; unsigned int u; } c; c.f = f;
  unsigned int u = c.u;
  return (unsigned short)((u + 0x7FFFu + ((u >> 16) & 1u)) >> 16);  // RNE
}
__device__ __forceinline__ float bf2f(unsigned short h) {
  union { unsigned int u; float f; } c; c.u = ((unsigned int)h) << 16;
  return c.f;
}

__device__ __forceinline__ void gld16(const void* g, void* l) {
  using gptr_t = const __attribute__((address_space(1))) void*;
  using lptr_t = __attribute__((address_space(3))) void*;
  __builtin_amdgcn_global_load_lds((gptr_t)(uintptr_t)g,
                                   (lptr_t)(uint32_t)(uintptr_t)l, 16, 0, 0);
}

// TBxTB tile GEMM core, K fixed = 512: C[m][n] = sum_k A[m0+m][k] * B[n0+n][k]
// 3-buffer pipeline, 2 stages in flight across barriers (counted vmcnt, never 0
// until the tail).  16-B granule XOR swizzle kills the 8-way ds_read_b128 bank
// conflict of the [row][32] bf16 layout (staging pre-swizzles the GLOBAL source
// column; ds_read applies the same XOR).  T5 setprio around the MFMA cluster.
template <int TB, bool SAME>
__device__ __forceinline__ void gemm_tile(const unsigned short* __restrict__ A, int lda,
                                          const unsigned short* __restrict__ B, int ldb,
                                          int m0, int n0, f32x4 (&acc)[TB / 32][TB / 32]) {
  static_assert(TB == 64 || TB == 128, "TB");
  constexpr int FR = TB / 32;         // MFMA frags per wave dim
  constexpr int LJ = (TB * 4) / 256;  // 16B loads per thread per matrix per stage
  constexpr int LPS = SAME ? LJ : 2 * LJ;  // loads in flight per stage
  constexpr int NK = 512 / BK;        // 16 K-steps
  __shared__ unsigned short sA[3][TB * BK];
  __shared__ unsigned short sB[3][TB * BK];
  const int tid = threadIdx.x;
  const int lane = tid & 63;
  const int w = tid >> 6;
  const int wm = w >> 1, wn = w & 1;
  const int quad = lane >> 4, l16 = lane & 15;
  const int sq = (quad ^ ((l16 >> 1) & 3)) * 8;  // swizzled k-granule (elems)

#pragma unroll
  for (int mi = 0; mi < FR; mi++)
#pragma unroll
    for (int ni = 0; ni < FR; ni++) acc[mi][ni] = f32x4{0.f, 0.f, 0.f, 0.f};

  auto stage = [&](int bb, int kt) {
    const int kk = kt * BK;
#pragma unroll
    for (int j = 0; j < LJ; j++) {
      const int slot = w * (LJ * 64) + j * 64 + lane;  // physical 16B granule
      const int row = slot >> 2;
      const int col = ((slot & 3) ^ ((slot >> 3) & 3)) * 8;  // pre-swizzled src
      const int basegr = w * (LJ * 64) + j * 64;  // wave-uniform LDS base
      gld16(A + (size_t)(m0 + row) * lda + kk + col, (char*)sA[bb] + (size_t)basegr * 16);
      if constexpr (!SAME)
        gld16(B + (size_t)(n0 + row) * ldb + kk + col, (char*)sB[bb] + (size_t)basegr * 16);
    }
  };

  auto compute = [&](int bb) {
    const unsigned short* as = sA[bb];
    const unsigned short* bs = SAME ? sA[bb] : sB[bb];
    bf16x8 af[FR], bfr[FR];
#pragma unroll
    for (int mi = 0; mi < FR; mi++)
      af[mi] = *(const bf16x8*)&as[(wm * (TB / 2) + mi * 16 + l16) * BK + sq];
#pragma unroll
    for (int ni = 0; ni < FR; ni++)
      bfr[ni] = *(const bf16x8*)&bs[(wn * (TB / 2) + ni * 16 + l16) * BK + sq];
    __builtin_amdgcn_s_setprio(1);
#pragma unroll
    for (int mi = 0; mi < FR; mi++)
#pragma unroll
      for (int ni = 0; ni < FR; ni++)
        acc[mi][ni] = __builtin_amdgcn_mfma_f32_16x16x32_bf16(af[mi], bfr[ni],
                                                              acc[mi][ni], 0, 0, 0);
    __builtin_amdgcn_s_setprio(0);
  };

  stage(0, 0);
  stage(1, 1);
  stage(2, 2);
#pragma unroll
  for (int kt = 0; kt < NK; ++kt) {
    if (kt < NK - 2) { vmw<2 * LPS>(); }       // stage kt done, 2 in flight
    else if (kt == NK - 2) { vmw<LPS>(); }
    else { vmw<0>(); }
    BAR;
    compute(kt % 3);
    BAR;
    if (kt < NK - 3) stage(kt % 3, kt + 3);
  }
}

// ---- prep: X fp32 -> Xb bf16 + Xt bf16 + colsum, WAVE-PRIVATE, no s_barrier ----
// Each wave owns a 64n x 32d tile and a private 4KB LDS buffer; the only sync is
// a wave-local lgkmcnt(0).  n stored permuted within the 64-block (pos q*8+i =
// source n q+8i) so every memory op is a contiguous 16B vector with 128B wave
// segments.  LDS granule position XOR-swizzled by (col>>2)&7: conflict-minimal
// on both write and read.  Colsum via 3-step shfl + 32 atomics/wave.
__global__ __launch_bounds__(256) void prep_kernel(const float* __restrict__ X,
                                                   unsigned short* __restrict__ Xb,
                                                   unsigned short* __restrict__ Xt,
                                                   float* __restrict__ mean_x) {
  __shared__ unsigned short sw[4][64 * 32];
  const int t = threadIdx.x;
  const int w = t >> 6, l = t & 63;
  const int g = blockIdx.x * 4 + w;     // wave-tile id, 0..8191
  const int d0 = (g & 15) * 32;
  const int n64 = (g >> 4) * 64;        // global n (0..32767)
  const int b = n64 >> 13, nb = n64 & 8191;
  const int a = l >> 3, q = l & 7;
  const int c0 = q * 4;
  unsigned short* myw = sw[w];

  f32x4 v[8];
#pragma unroll
  for (int i = 0; i < 8; i++)
    v[i] = *(const f32x4*)(X + (size_t)(n64 + a + 8 * i) * 512 + d0 + c0);
  __builtin_amdgcn_sched_barrier(0);  // all 8 loads in flight before any use

  u16x4 o[8];
#pragma unroll
  for (int i = 0; i < 8; i++)
#pragma unroll
    for (int j = 0; j < 4; j++) o[i][j] = f2bf(v[i][j]);

  // LDS transposed write: logical granule a at column c holds rows {a+8i}
#pragma unroll
  for (int j = 0; j < 4; j++) {
    u16x8 wv;
#pragma unroll
    for (int i = 0; i < 8; i++) wv[i] = o[i][j];
    const int c = c0 + j;
    const int pos = a ^ ((c >> 2) & 7);
    *(u16x8*)&myw[c * 64 + pos * 8] = wv;
  }

  // Xb stores issue while LDS writes drain
#pragma unroll
  for (int i = 0; i < 8; i++)
    *(u16x4*)(Xb + (size_t)(n64 + a + 8 * i) * 512 + d0 + c0) = o[i];

  asm volatile("s_waitcnt lgkmcnt(0)" ::: "memory");

  float cs[4];
#pragma unroll
  for (int h = 0; h < 4; h++) {
    const int cp = a + 8 * h;  // d-row 0..31
    const int pos = q ^ ((cp >> 2) & 7);
    u16x8 val = *(const u16x8*)&myw[cp * 64 + pos * 8];
    *(u16x8*)(Xt + (size_t)(b * 512 + d0 + cp) * 8192 + nb + q * 8) = val;
    float ss = 0.f;
#pragma unroll
    for (int jj = 0; jj < 8; jj++) ss += bf2f(val[jj]);
    cs[h] = ss;
  }
#pragma unroll
  for (int h = 0; h < 4; h++) {
    float sv = cs[h];
    sv += __shfl_xor(sv, 1);
    sv += __shfl_xor(sv, 2);
    sv += __shfl_xor(sv, 4);
    if (q == 0) atomicAdd(&mean_x[b * 512 + d0 + a + 8 * h], sv);
  }
}

// ---- W casts + zero-init of mean_x (runs before prep in-stream) ----
__global__ __launch_bounds__(256) void prep_w_kernel(const float* __restrict__ Wv,
                                                     const float* __restrict__ Wth,
                                                     unsigned short* __restrict__ Wvb,
                                                     unsigned short* __restrict__ Wtb,
                                                     float* __restrict__ mean_x) {
  const int blk = blockIdx.x;
  const int t = threadIdx.x;
  if (blk == 0) {
#pragma unroll
    for (int i = 0; i < 8; i++) mean_x[t + i * 256] = 0.f;
  }
  const float* src = (blk < 128) ? Wv : Wth;
  unsigned short* dst = (blk < 128) ? Wvb : Wtb;
  const int i = (blk & 127) * 256 + t;
  const f32x4* pp = (const f32x4*)(src + (size_t)i * 8);
  f32x4 v0 = pp[0], v1 = pp[1];
  u16x8 o;
  o[0] = f2bf(v0[0]); o[1] = f2bf(v0[1]); o[2] = f2bf(v0[2]); o[3] = f2bf(v0[3]);
  o[4] = f2bf(v1[0]); o[5] = f2bf(v1[1]); o[6] = f2bf(v1[2]); o[7] = f2bf(v1[3]);
  *(u16x8*)(dst + (size_t)i * 8) = o;
}

// ---- G = Xt Xt^T (per batch), split-K=16, upper tiles only ----
// Grid (z=64, t=10): the 10 blocks of one z (same 512KB Xt k-slice) are 64
// dispatch-indices apart -> same XCD under %8 round-robin -> L2 slice reuse.
static __device__ const int TI[10] = {0, 0, 0, 0, 1, 1, 1, 2, 2, 3};
static __device__ const int TJ[10] = {0, 1, 2, 3, 1, 2, 3, 2, 3, 3};

__global__ __launch_bounds__(256) void g_gemm_kernel(const unsigned short* __restrict__ Xt,
                                                     float* __restrict__ G_part) {
  const int t = blockIdx.y;        // 0..9 upper tile
  const int z = blockIdx.x;        // b*16 + s
  const int b = z >> 4, s = z & 15;
  const int m0 = TI[t] * 128, n0 = TJ[t] * 128;
  const unsigned short* A = Xt + (size_t)b * 512 * 8192 + (size_t)s * 512;
  f32x4 acc[4][4];
  if (m0 == n0)
    gemm_tile<128, true>(A, 8192, A, 8192, m0, n0, acc);
  else
    gemm_tile<128, false>(A, 8192, A, 8192, m0, n0, acc);
  float* Cp = G_part + ((size_t)z * 10 + t) * 16384;  // tile stored [n_local][m_local]
  const int tid = threadIdx.x, lane = tid & 63, w = tid >> 6;
  const int wm = w >> 1, wn = w & 1, quad = lane >> 4, l16 = lane & 15;
#pragma unroll
  for (int mi = 0; mi < 4; mi++)
#pragma unroll
    for (int ni = 0; ni < 4; ni++) {
      const int ml = wm * 64 + mi * 16 + quad * 4;
      const int nl = wn * 64 + ni * 16 + l16;
      *(f32x4*)(Cp + (size_t)nl * 128 + ml) = acc[mi][ni];
    }
}

// sum slices, scale, cast bf16, write G + mirror.  Blocks >= 320: meanV part.
__global__ __launch_bounds__(256) void g_fin_kernel(const float* __restrict__ G_part,
                                                    unsigned short* __restrict__ Gb,
                                                    const float* __restrict__ mean_x,
                                                    const float* __restrict__ Wv,
                                                    float* __restrict__ meanV) {
  const int blk = blockIdx.x;  // 4*10*8 + 8
  if (blk >= 320) {
    // meanV[b*512+e] = (1/8192) sum_d mean_x[b*512+d] * Wv[e*512+d]
    const int idx = (blk - 320) * 256 + threadIdx.x;
    const int b = idx >> 9, e = idx & 511;
    const float* mx = mean_x + b * 512;
    const float* wr = Wv + (size_t)e * 512;
    float s = 0.f;
    for (int d = 0; d < 512; d += 4) {
      f32x4 a = *(const f32x4*)(mx + d);
      f32x4 w4 = *(const f32x4*)(wr + d);
      s += a[0] * w4[0] + a[1] * w4[1] + a[2] * w4[2] + a[3] * w4[3];
    }
    meanV[idx] = s * (1.f / 8192.f);
    return;
  }
  const int b = blk / 80, rem = blk % 80;
  const int t = rem >> 3, cc = rem & 7;
  const int i = TI[t], j = TJ[t];
  const int m0 = i * 128, n0 = j * 128;
  const int tid = threadIdx.x;
  const int np = cc * 16 + (tid >> 4);
  const int mp = (tid & 15) * 8;
  f32x4 s0 = f32x4{0.f, 0.f, 0.f, 0.f}, s1 = f32x4{0.f, 0.f, 0.f, 0.f};
#pragma unroll
  for (int s = 0; s < 16; s++) {
    const float* p = G_part + (((size_t)(b * 16 + s)) * 10 + t) * 16384 + (size_t)np * 128 + mp;
    s0 += *(const f32x4*)p;
    s1 += *(const f32x4*)(p + 4);
  }
  const float scale = (float)(1.0 / (8192.0 * 22.627416997969522));
  unsigned short h[8];
#pragma unroll
  for (int r = 0; r < 4; r++) { h[r] = f2bf(s0[r] * scale); h[r + 4] = f2bf(s1[r] * scale); }
  unsigned short* Gbb = Gb + (size_t)b * 262144;
#pragma unroll
  for (int r = 0; r < 8; r++)
    Gbb[(size_t)(m0 + mp + r) * 512 + (n0 + np)] = h[r];
  if (i != j) {
    u16x8 o;
#pragma unroll
    for (int r = 0; r < 8; r++) o[r] = h[r];
    *(u16x8*)(Gbb + (size_t)(n0 + np) * 512 + (m0 + mp)) = o;
  }
}

// small batched GEMM, row-major bf16 C: C[m][n] = sum_k A[m][k]B[n][k], all 512.
// TB=64 tiles: 256 blocks instead of 64 -> whole chip busy.
__global__ __launch_bounds__(256) void gemm_rm_kernel(const unsigned short* __restrict__ A,
                                                      const unsigned short* __restrict__ B,
                                                      unsigned short* __restrict__ C,
                                                      size_t Abs, size_t Bbs) {
  const int b = blockIdx.z;
  const int m0 = blockIdx.x * 64, n0 = blockIdx.y * 64;
  f32x4 acc[2][2];
  gemm_tile<64, false>(A + (size_t)b * Abs, 512, B + (size_t)b * Bbs, 512, m0, n0, acc);
  unsigned short* Cb = C + (size_t)b * 262144;
  const int tid = threadIdx.x, lane = tid & 63, w = tid >> 6;
  const int wm = w >> 1, wn = w & 1, quad = lane >> 4, l16 = lane & 15;
#pragma unroll
  for (int mi = 0; mi < 2; mi++)
#pragma unroll
    for (int ni = 0; ni < 2; ni++) {
      const int m = m0 + wm * 32 + mi * 16 + quad * 4;
      const int n = n0 + wn * 32 + ni * 16 + l16;
#pragma unroll
      for (int r = 0; r < 4; r++)
        Cb[(size_t)(m + r) * 512 + n] = f2bf(acc[mi][ni][r]);
    }
}

// final: out[m][e] = sum_d Xb[m][d]*kvt_b[e][d] + meanV[b][e]
// 1-D grid, bijective remap: the 4 n-tiles sharing an Xb m-tile sit 8 apart in
// dispatch order -> same XCD under %8 round-robin -> Xb tile fetched once/XCD.
__global__ __launch_bounds__(256) void gemm_out_kernel(
    const unsigned short* __restrict__ Xb, const unsigned short* __restrict__ kvt,
    const float* __restrict__ meanV, float* __restrict__ out) {
  const int D = blockIdx.x;                      // 0..1023
  const int gm = (D & 7) + ((D >> 5) << 3);      // m-tile 0..255
  const int nt = (D >> 3) & 3;                   // n-tile 0..3
  const int m0 = gm * 128, n0 = nt * 128;
  const int b = gm >> 6;
  const unsigned short* Bm = kvt + (size_t)b * 262144;
  f32x4 acc[4][4];
  gemm_tile<128, false>(Xb, 512, Bm, 512, m0, n0, acc);
  const int tid = threadIdx.x, lane = tid & 63, w = tid >> 6;
  const int wm = w >> 1, wn = w & 1, quad = lane >> 4, l16 = lane & 15;
#pragma unroll
  for (int ni = 0; ni < 4; ni++) {
    const int e = n0 + wn * 64 + ni * 16 + l16;
    const float mu = meanV[b * 512 + e];
#pragma unroll
    for (int mi = 0; mi < 4; mi++) {
      const int m = m0 + wm * 64 + mi * 16 + quad * 4;
#pragma unroll
      for (int r = 0; r < 4; r++)
        out[(size_t)(m + r) * 512 + e] = acc[mi][ni][r] + mu;
    }
  }
}

extern "C" void kernel_launch(void* const* d_in, const int* in_sizes, int n_in,
                              void* d_out, int out_size, void* d_ws, size_t ws_size,
                              hipStream_t stream) {
  const float* X = (const float*)d_in[0];
  const float* Wv = (const float*)d_in[1];
  const float* Wth = (const float*)d_in[2];
  float* out = (float*)d_out;
  char* ws = (char*)d_ws;

  unsigned short* Xb = (unsigned short*)(ws);                  // 32 MB
  unsigned short* Xt = (unsigned short*)(ws + 33554432ull);    // 32 MB
  float* G_part = (float*)(ws + 67108864ull);                  // 41.94 MB
  unsigned short* Gb = (unsigned short*)(ws + 109051904ull);   // 2 MB
  unsigned short* Ht = (unsigned short*)(ws + 111149056ull);   // 2 MB
  unsigned short* kvt = (unsigned short*)(ws + 113246208ull);  // 2 MB
  unsigned short* Wvb = (unsigned short*)(ws + 115343360ull);  // 0.5 MB
  unsigned short* Wtb = (unsigned short*)(ws + 115867648ull);  // 0.5 MB
  float* mean_x = (float*)(ws + 116391936ull);                 // 8 KB
  float* meanV = (float*)(ws + 116400128ull);                  // 8 KB

  prep_w_kernel<<<256, 256, 0, stream>>>(Wv, Wth, Wvb, Wtb, mean_x);
  prep_kernel<<<2048, 256, 0, stream>>>(X, Xb, Xt, mean_x);

  g_gemm_kernel<<<dim3(64, 10), 256, 0, stream>>>(Xt, G_part);
  g_fin_kernel<<<328, 256, 0, stream>>>(G_part, Gb, mean_x, Wv, meanV);

  gemm_rm_kernel<<<dim3(8, 8, 4), 256, 0, stream>>>(Wvb, Gb, Ht, 0, 262144);
  gemm_rm_kernel<<<dim3(8, 8, 4), 256, 0, stream>>>(Ht, Wtb, kvt, 262144, 0);

  gemm_out_kernel<<<1024, 256, 0, stream>>>(Xb, kvt, meanV, out);
}